// Round 8
// baseline (322.979 us; speedup 1.0000x reference)
//
#include <hip/hip_runtime.h>
#include <cstdio>
#include <cstdint>

typedef unsigned long long u64;

// ---------------- problem constants ----------------
static const int kNV = 200000;
static const int kNT = 800000;
static const int kNUV = 895;                       // ceil(sqrt((2*NT+1)//2))
#define UVS_ROWS   3204100LL                       // kNUV*kNUV*4
#define UVS_FLOATS 6408200LL                       // UVS_ROWS*2
#define CAP 3300000                                // max crossing-edge instances (<= 4*NT = 3.2M)

// counting-sort geometry
#define NH 392                                     // classify/hist/scatter/unsort blocks
#define TILE_T 2048                                // tets per block (NH*TILE_T >= kNT)
#define BINW 256                                   // a-values per coarse bin
#define NBIN 782                                   // ceil(200000/256)
#define SUBSH 15                                   // sub-bucket = (a, b>>SUBSH)
#define FINEB 2048                                 // BINW * (1<<(18-SUBSH)) fine cursors

__device__ const int c_tri[16][6] = {
    {-1,-1,-1,-1,-1,-1},{1,0,2,-1,-1,-1},{4,0,3,-1,-1,-1},{1,4,2,1,3,4},
    {3,1,5,-1,-1,-1},{2,3,0,2,5,3},{1,4,0,1,5,4},{4,2,5,-1,-1,-1},
    {4,5,2,-1,-1,-1},{4,1,0,4,5,1},{3,2,0,3,5,2},{1,3,5,-1,-1,-1},
    {4,1,2,4,3,1},{3,0,4,-1,-1,-1},{2,0,1,-1,-1,-1},{-1,-1,-1,-1,-1,-1}};
__device__ const int c_ntri[16]   = {0,1,1,2,1,2,2,1,1,2,2,1,2,1,1,0};
__device__ const int c_ncross[16] = {0,3,3,4,3,4,4,3,3,4,4,3,4,3,3,0};
__device__ const int c_edges[12] = {0,1,0,2,0,3,1,2,1,3,2,3};

// psum packing: m1 <<44 | m2 <<24 | ncross (m1,m2 totals < 2^20, ncross total < 2^24)
#define PK(m1,m2,nc) (((u64)(m1) << 44) | ((u64)(m2) << 24) | (u64)(nc))
// ebin packing: a <<40 | b <<22 | seq (a,b < 2^18, seq < 2^22); key36 = p>>22; group = key36>>SUBSH

// ---------------- generic exclusive scan (templated, 3 kernels) ----------------
#define SCAN_B 256
#define SCAN_I 8
#define SCAN_TILE (SCAN_B*SCAN_I)

template<typename T>
__global__ void k_scan_partial(const T* __restrict__ in, T* __restrict__ partials, int n){
  __shared__ T sm[SCAN_B];
  int b = blockIdx.x;
  long long base = (long long)b*SCAN_TILE;
  T sum = 0;
  for (int i = threadIdx.x; i < SCAN_TILE; i += SCAN_B){
    long long idx = base + i;
    if (idx < n) sum += in[idx];
  }
  sm[threadIdx.x] = sum; __syncthreads();
  for (int s = SCAN_B/2; s > 0; s >>= 1){
    if ((int)threadIdx.x < s) sm[threadIdx.x] += sm[threadIdx.x + s];
    __syncthreads();
  }
  if (threadIdx.x == 0) partials[b] = sm[0];
}

template<typename T>
__global__ void k_scan_blocksums(T* __restrict__ partials, int nb, T* __restrict__ total_out){
  __shared__ T sm[SCAN_B];
  T carry = 0;
  for (int base = 0; base < nb; base += SCAN_B){
    int i = base + (int)threadIdx.x;
    T v = (i < nb) ? partials[i] : (T)0;
    sm[threadIdx.x] = v; __syncthreads();
    for (int off = 1; off < SCAN_B; off <<= 1){
      T t = ((int)threadIdx.x >= off) ? sm[threadIdx.x - off] : (T)0;
      __syncthreads();
      sm[threadIdx.x] += t;
      __syncthreads();
    }
    if (i < nb) partials[i] = carry + sm[threadIdx.x] - v;  // exclusive
    T tilesum = sm[SCAN_B-1];
    __syncthreads();
    carry += tilesum;
  }
  if (threadIdx.x == 0 && total_out) *total_out = carry;
}

template<typename T>
__global__ void k_scan_apply(const T* __restrict__ in, T* __restrict__ out,
                             const T* __restrict__ partials, int n){
  __shared__ T sm[SCAN_B];
  int b = blockIdx.x;
  long long base = (long long)b*SCAN_TILE + (long long)threadIdx.x*SCAN_I;
  T v[SCAN_I]; T s = 0;
  #pragma unroll
  for (int k = 0; k < SCAN_I; k++){ long long idx = base + k; v[k] = (idx < n) ? in[idx] : (T)0; s += v[k]; }
  sm[threadIdx.x] = s; __syncthreads();
  for (int off = 1; off < 256; off <<= 1){
    T t = ((int)threadIdx.x >= off) ? sm[threadIdx.x - off] : (T)0;
    __syncthreads();
    sm[threadIdx.x] += t;
    __syncthreads();
  }
  T excl = sm[threadIdx.x] - s + partials[b];
  #pragma unroll
  for (int k = 0; k < SCAN_I; k++){ long long idx = base + k; if (idx < n) out[idx] = excl; excl += v[k]; }
}

template<typename T>
static void run_scan(const T* in, T* out, int n, T* partials, hipStream_t s){
  int nb = (n + SCAN_TILE - 1) / SCAN_TILE;
  k_scan_partial<T><<<nb, SCAN_B, 0, s>>>(in, partials, n);
  k_scan_blocksums<T><<<1, SCAN_B, 0, s>>>(partials, nb, out + n);  // total -> out[n]
  k_scan_apply<T><<<nb, SCAN_B, 0, s>>>(in, out, partials, n);
}

// ---------------- pipeline kernels ----------------

// fused: per-tet occupancy pattern + (m1,m2,ncross) pack + coarse-bin histogram
__global__ void k_classify_hist(const int* __restrict__ tet, const float* __restrict__ sdf,
                                int* __restrict__ tetinfo, u64* __restrict__ pk,
                                int* __restrict__ blockHist){
  __shared__ int h[NBIN];
  int blk = blockIdx.x;
  for (int j = threadIdx.x; j < NBIN; j += 256) h[j] = 0;
  __syncthreads();
  int t0 = blk*TILE_T;
  for (int k = 0; k < TILE_T/256; k++){
    int t = t0 + k*256 + threadIdx.x;
    if (t < kNT){
      int4 v4 = ((const int4*)tet)[t];
      int pat = ((sdf[v4.x] > 0.0f) ? 1 : 0) | ((sdf[v4.y] > 0.0f) ? 2 : 0)
              | ((sdf[v4.z] > 0.0f) ? 4 : 0) | ((sdf[v4.w] > 0.0f) ? 8 : 0);
      tetinfo[t] = pat;
      int nt_ = c_ntri[pat];
      pk[t] = PK(nt_ == 1, nt_ == 2, c_ncross[pat]);
      if (pat != 0 && pat != 15){
        int vv[4] = {v4.x, v4.y, v4.z, v4.w};
        #pragma unroll
        for (int e = 0; e < 6; e++){
          int i0 = c_edges[2*e], i1 = c_edges[2*e+1];
          if (((pat >> i0) & 1) != ((pat >> i1) & 1)){
            int a = vv[i0], b = vv[i1]; if (a > b){ int tm = a; a = b; b = tm; }
            atomicAdd(&h[a >> 8], 1);
          }
        }
      }
    }
  }
  __syncthreads();
  for (int j = threadIdx.x; j < NBIN; j += 256) blockHist[j*NH + blk] = h[j];  // bin-major
}

// scatter instances to bin-grouped buffer via LDS cursors (payload = seq)
__global__ void k_scatter(const int* __restrict__ tet, const int* __restrict__ tetinfo,
                          const u64* __restrict__ psum, const int* __restrict__ bhScan,
                          u64* __restrict__ ebin){
  __shared__ int c[NBIN];
  int blk = blockIdx.x;
  for (int j = threadIdx.x; j < NBIN; j += 256) c[j] = bhScan[j*NH + blk];
  __syncthreads();
  int t0 = blk*TILE_T;
  for (int k = 0; k < TILE_T/256; k++){
    int t = t0 + k*256 + threadIdx.x;
    if (t < kNT){
      int pat = tetinfo[t];
      if (pat != 0 && pat != 15){
        int4 v4 = ((const int4*)tet)[t];
        int vv[4] = {v4.x, v4.y, v4.z, v4.w};
        int seq = (int)(psum[t] & 0xFFFFFF);
        #pragma unroll
        for (int e = 0; e < 6; e++){
          int i0 = c_edges[2*e], i1 = c_edges[2*e+1];
          if (((pat >> i0) & 1) != ((pat >> i1) & 1)){
            int a = vv[i0], b = vv[i1]; if (a > b){ int tm = a; a = b; b = tm; }
            int pos = atomicAdd(&c[a >> 8], 1);
            ebin[pos] = ((u64)(unsigned)a << 40) | ((u64)(unsigned)b << 22) | (unsigned)seq;
            seq++;
          }
        }
      }
    }
  }
}

// per coarse bin: regroup by fine key (a&255)<<3 | b>>15; posmap[binpos] = finalpos.
// efin ends up globally sorted by (a, b>>15) -> groups for k_flags are tiny (k ~ 1.5).
__global__ void k_fine(const int* __restrict__ bhScan, const u64* __restrict__ ebin,
                       u64* __restrict__ efin, int* __restrict__ posmap){
  __shared__ int h[FINEB];
  __shared__ int ss[256];
  int bin = blockIdx.x;
  int binStart = bhScan[bin*NH];
  int binEnd   = bhScan[(bin+1)*NH];     // scan stores total at [n] for the last bin
  int a0 = bin << 8;
  for (int j = threadIdx.x; j < FINEB; j += 256) h[j] = 0;
  __syncthreads();
  for (int i = binStart + threadIdx.x; i < binEnd; i += 256){
    u64 p = ebin[i];
    int a = (int)(p >> 40);
    int bh = (int)((p >> 22) & 0x3FFFF) >> SUBSH;
    atomicAdd(&h[((a - a0) << 3) | bh], 1);
  }
  __syncthreads();
  // exclusive scan of h[2048] with 256 threads (8 elements each)
  int tid = threadIdx.x;
  int base8 = tid*8;
  int loc[8]; int s = 0;
  #pragma unroll
  for (int q = 0; q < 8; q++){ loc[q] = h[base8+q]; s += loc[q]; }
  ss[tid] = s; __syncthreads();
  for (int off = 1; off < 256; off <<= 1){
    int v = (tid >= off) ? ss[tid - off] : 0;
    __syncthreads();
    ss[tid] += v;
    __syncthreads();
  }
  int excl = ss[tid] - s;
  #pragma unroll
  for (int q = 0; q < 8; q++){ h[base8+q] = excl; excl += loc[q]; }
  __syncthreads();
  // regroup: h serves as per-fine-key cursors (exclusive offsets)
  for (int i = binStart + tid; i < binEnd; i += 256){
    u64 p = ebin[i];
    int a = (int)(p >> 40);
    int bh = (int)((p >> 22) & 0x3FFFF) >> SUBSH;
    int pos = binStart + atomicAdd(&h[((a - a0) << 3) | bh], 1);
    efin[pos] = p;
    posmap[i] = pos;
  }
}

// item-parallel first/rank/off over (a,b>>15)-sorted efin, LDS window with halos.
#define FB 256
#define FH 32
#define FW (FB + 2*FH)   // 320
__global__ void k_flags(const u64* __restrict__ efin, const int* __restrict__ totp,
                        int* __restrict__ firstI, unsigned* __restrict__ meta){
  __shared__ u64 ld[FW];
  __shared__ unsigned char fl[FW];
  int total = *totp;
  int tid = threadIdx.x;
  long long base = (long long)blockIdx.x * FB;
  long long gi = base + tid;
  if (base >= total){                       // pure tail block: zero-fill, no window
    if (gi < CAP){ firstI[gi] = 0; meta[gi] = 0; }
    return;
  }
  for (int x = tid; x < FW; x += FB){
    long long g = base - FH + x;
    ld[x] = (g >= 0 && g < total) ? (efin[g] >> 22) : ~0ULL;   // key36 = a<<18 | b
  }
  __syncthreads();
  // phase 1: first-occurrence flags for window + halos (left scan within group)
  for (int x = tid; x < FW; x += FB){
    u64 key = ld[x];
    u64 grp = key >> SUBSH;
    unsigned char f = 1;
    for (int y = x-1; y >= 0; y--){
      u64 ky = ld[y];
      if ((ky >> SUBSH) != grp) break;
      if (ky == key){ f = 0; break; }
    }
    fl[x] = f;
  }
  __syncthreads();
  // phase 2: per item: group range, rank = #distinct smaller keys in group
  if (gi < total){
    int x = FH + tid;
    u64 key = ld[x];
    u64 grp = key >> SUBSH;
    int sx = x; while (sx > 0 && (ld[sx-1] >> SUBSH) == grp) sx--;
    int ex = x+1; while (ex < FW && (ld[ex] >> SUBSH) == grp) ex++;
    int first, rank, off;
    if (sx > 0 && ex < FW){
      first = fl[x];
      int rk = 0;
      for (int y = sx; y < ex; y++) if (fl[y] && ld[y] < key) rk++;
      rank = rk; off = x - sx;
    } else {
      // slow path: group spans past the LDS window (group > 32 items; statistically never)
      u64 keyg = efin[gi] >> 22;
      u64 grpg = keyg >> SUBSH;
      long long s = gi; while (s > 0 && ((efin[s-1] >> 22) >> SUBSH) == grpg) s--;
      long long e = gi + 1; while (e < total && ((efin[e] >> 22) >> SUBSH) == grpg) e++;
      int f = 1;
      for (long long j = s; j < gi; j++) if ((efin[j] >> 22) == keyg){ f = 0; break; }
      int rk = 0;
      for (long long j = s; j < e; j++){
        u64 kj = efin[j] >> 22;
        if (kj < keyg){
          bool fj = true;
          for (long long l = s; l < j; l++) if ((efin[l] >> 22) == kj){ fj = false; break; }
          if (fj) rk++;
        }
      }
      first = f; rank = rk; off = (int)(gi - s);
    }
    firstI[gi] = first;
    meta[gi] = (unsigned)rank | ((unsigned)off << 12) | ((unsigned)first << 24);
  } else if (gi < CAP){
    firstI[gi] = 0;      // straddling block's tail: zero-fill for exact CAP-length scan
    meta[gi] = 0;
  }
}

// item-parallel: r = fscan[group_start] + rank; emit verts (firsts) + rankFin (SEQUENTIAL)
__global__ void k_emit(const u64* __restrict__ efin, const int* __restrict__ totp,
                       const int* __restrict__ fscan, const unsigned* __restrict__ meta,
                       const float* __restrict__ pos, const float* __restrict__ sdf,
                       float* __restrict__ out, int* __restrict__ rankFin){
  int total = *totp;
  int i = blockIdx.x*256 + threadIdx.x;
  if (i >= total) return;
  u64 p = efin[i];
  unsigned m = meta[i];
  int rank = m & 0xFFF, off = (m >> 12) & 0xFFF, first = (m >> 24) & 1;
  int r = fscan[i - off] + rank;
  rankFin[i] = r;                          // sequential write (no cross-XCD false sharing)
  if (first){
    int a = (int)(p >> 40);
    int b = (int)((p >> 22) & 0x3FFFF);
    float sa = sdf[a], sb = sdf[b];
    float denom = sa - sb;               // s = [sa,-sb]; never 0 for a crossing edge
    float w0 = (-sb) / denom;
    float w1 = sa / denom;
    out[3LL*r + 0] = pos[3*a+0]*w0 + pos[3*b+0]*w1;
    out[3LL*r + 1] = pos[3*a+1]*w0 + pos[3*b+1]*w1;
    out[3LL*r + 2] = pos[3*a+2]*w0 + pos[3*b+2]*w1;
  }
}

// inverse permutation with XCD locality: block blk walks its own bin-runs; every
// rankBySeq write lands in blk's contiguous ~24KB seq window (single-XCD lines);
// gathers (posmap->efin/rankFin) stay inside each ~12KB coarse-bin window.
__global__ void k_unsort(const int* __restrict__ bhScan, const int* __restrict__ posmap,
                         const u64* __restrict__ efin, const int* __restrict__ rankFin,
                         int* __restrict__ rankBySeq){
  int blk = blockIdx.x;
  int tid = threadIdx.x;
  for (int j = tid; j < NBIN; j += 256){
    int f = j*NH + blk;
    int start = bhScan[f], end = bhScan[f+1];
    for (int pos = start; pos < end; pos++){
      int fp = posmap[pos];
      int seq = (int)(efin[fp] & 0x3FFFFF);
      rankBySeq[seq] = rankFin[fp];
    }
  }
}

// faces + uv_idx: er[j] = rankBySeq[seq + j] — fully sequential reads
__global__ void k_faces(const int* __restrict__ tetinfo, const u64* __restrict__ psum,
                        const int* __restrict__ fscan, const int* __restrict__ rankBySeq,
                        float* __restrict__ out){
  int t = blockIdx.x*256 + threadIdx.x; if (t >= kNT) return;
  int pat = tetinfo[t];
  int nt_ = c_ntri[pat];
  if (nt_ == 0) return;
  u64 tot = psum[kNT];
  int Nm1 = (int)(tot >> 44), Nm2 = (int)((tot >> 24) & 0xFFFFF);
  int Ne = fscan[CAP];
  long long faces_off = 3LL*Ne;
  long long uvidx_off = faces_off + 3LL*((long long)Nm1 + 2LL*Nm2) + UVS_FLOATS;
  u64 ps = psum[t];
  int m1v = (int)(ps >> 44), m2v = (int)((ps >> 24) & 0xFFFFF);
  int seq = (int)(ps & 0xFFFFFF);
  int er[6];
  int j = 0;
  #pragma unroll
  for (int e = 0; e < 6; e++){
    int i0 = c_edges[2*e], i1 = c_edges[2*e+1];
    if (((pat >> i0) & 1) != ((pat >> i1) & 1)){
      er[e] = rankBySeq[seq + j];
      j++;
    } else er[e] = -1;
  }
  for (int k = 0; k < nt_; k++){
    long long row = (nt_ == 1) ? (long long)m1v : ((long long)Nm1 + 2LL*m2v + k);
    #pragma unroll
    for (int c = 0; c < 3; c++){
      int slot = c_tri[pat][3*k + c];
      out[faces_off + 3*row + c] = (float)er[slot];
    }
    out[uvidx_off + 3*row + 0] = (float)(4*t);
    out[uvidx_off + 3*row + 1] = (float)(4*t + k + 1);
    out[uvidx_off + 3*row + 2] = (float)(4*t + k + 2);
  }
}

__global__ void k_uvs(const u64* __restrict__ psum, const int* __restrict__ fscan,
                      float* __restrict__ out){
  long long r = (long long)blockIdx.x*256 + threadIdx.x;
  if (r >= UVS_ROWS) return;
  u64 tot = psum[kNT];
  int Nm1 = (int)(tot >> 44), Nm2 = (int)((tot >> 24) & 0xFFFFF);
  int Ne = fscan[CAP];
  long long off = 3LL*Ne + 3LL*((long long)Nm1 + 2LL*Nm2);
  int cell = (int)(r >> 2), k = (int)(r & 3);
  int iy = cell / kNUV, ix = cell - iy*kNUV;
  const float delta = (1.0f - 1.0f/895.0f) / 894.0f;   // linspace(0, 1-1/N, N) step, f32
  const float pad = 0.9f / 895.0f;
  float x = (float)ix * delta, y = (float)iy * delta;
  float u = x + ((k == 1 || k == 2) ? pad : 0.0f);
  float v = y + ((k >= 2) ? pad : 0.0f);
  out[off + 2*r]     = u;
  out[off + 2*r + 1] = v;
}

// ---------------- host ----------------
static inline int divup(int a, int b){ return (a + b - 1) / b; }

extern "C" void kernel_launch(void* const* d_in, const int* in_sizes, int n_in,
                              void* d_out, int out_size, void* d_ws, size_t ws_size,
                              hipStream_t stream){
  const float* pos = (const float*)d_in[0];
  const float* sdf = (const float*)d_in[1];
  const int*   tet = (const int*)d_in[2];
  float* out = (float*)d_out;

  char* ws = (char*)d_ws;
  size_t off = 0;
  auto alloc = [&](size_t bytes) -> char* {
    char* p = ws + off; off += (bytes + 255) & ~(size_t)255; return p;
  };
  int* tetinfo     = (int*)alloc((size_t)kNT*4);
  u64* pk          = (u64*)alloc((size_t)kNT*8);
  u64* psum        = (u64*)alloc((size_t)(kNT+1)*8);
  int* blockHist   = (int*)alloc((size_t)NBIN*NH*4);
  int* bhScan      = (int*)alloc((size_t)(NBIN*NH+1)*4);
  u64* ebin        = (u64*)alloc((size_t)CAP*8);
  u64* efin        = (u64*)alloc((size_t)CAP*8);
  int* posmap      = (int*)alloc((size_t)CAP*4);
  int* rankFin     = (int*)alloc((size_t)CAP*4);
  int* rankBySeq   = (int*)alloc((size_t)CAP*4);
  int* fscan       = (int*)alloc((size_t)(CAP+1)*4);
  u64* part64      = (u64*)alloc(4096*8);
  int* partI       = (int*)alloc(4096*4);
  // ebin is dead after k_fine: alias the flags outputs onto it
  int* firstI      = (int*)ebin;
  unsigned* meta   = (unsigned*)((char*)ebin + (size_t)CAP*4);
  if (off > ws_size){
    fprintf(stderr, "[dmtet] workspace too small: need %zu have %zu\n", off, ws_size);
    return;
  }

  k_classify_hist<<<NH, 256, 0, stream>>>(tet, sdf, tetinfo, pk, blockHist);
  run_scan<u64>(pk, psum, kNT, part64, stream);
  run_scan<int>(blockHist, bhScan, NBIN*NH, partI, stream);
  k_scatter<<<NH, 256, 0, stream>>>(tet, tetinfo, psum, bhScan, ebin);
  k_fine<<<NBIN, 256, 0, stream>>>(bhScan, ebin, efin, posmap);
  k_flags<<<divup(CAP,FB), FB, 0, stream>>>(efin, bhScan + NBIN*NH, firstI, meta);
  run_scan<int>(firstI, fscan, CAP, partI, stream);
  k_emit<<<divup(CAP,256), 256, 0, stream>>>(efin, bhScan + NBIN*NH, fscan, meta,
                                             pos, sdf, out, rankFin);
  k_unsort<<<NH, 256, 0, stream>>>(bhScan, posmap, efin, rankFin, rankBySeq);
  k_faces<<<divup(kNT,256), 256, 0, stream>>>(tetinfo, psum, fscan, rankBySeq, out);
  k_uvs<<<divup((int)UVS_ROWS,256), 256, 0, stream>>>(psum, fscan, out);
}

// Round 9
// 256.323 us; speedup vs baseline: 1.2600x; 1.2600x over previous
//
#include <hip/hip_runtime.h>
#include <cstdio>
#include <cstdint>

typedef unsigned long long u64;

// ---------------- problem constants ----------------
static const int kNV = 200000;
static const int kNT = 800000;
static const int kNUV = 895;                       // ceil(sqrt((2*NT+1)//2))
#define UVS_ROWS   3204100LL                       // kNUV*kNUV*4
#define UVS_FLOATS 6408200LL                       // UVS_ROWS*2
#define CAP 3300000                                // max crossing-edge instances (<= 4*NT = 3.2M)

// counting-sort geometry
#define NH 392                                     // classify/hist/scatter blocks
#define TILE_T 2048                                // tets per block (NH*TILE_T >= kNT)
#define BINW 256                                   // a-values per coarse bin
#define NBIN 782                                   // ceil(200000/256)
#define SUBSH 15                                   // group key = (a, b>>SUBSH)
#define FINEB 2048                                 // BINW * (1<<(18-SUBSH)) fine cursors

// flags/emit window geometry
#define FB 256
#define FH 32
#define FW (FB + 2*FH)   // 320
#define NFB ((CAP + FB - 1) / FB)   // 12891

__device__ const int c_tri[16][6] = {
    {-1,-1,-1,-1,-1,-1},{1,0,2,-1,-1,-1},{4,0,3,-1,-1,-1},{1,4,2,1,3,4},
    {3,1,5,-1,-1,-1},{2,3,0,2,5,3},{1,4,0,1,5,4},{4,2,5,-1,-1,-1},
    {4,5,2,-1,-1,-1},{4,1,0,4,5,1},{3,2,0,3,5,2},{1,3,5,-1,-1,-1},
    {4,1,2,4,3,1},{3,0,4,-1,-1,-1},{2,0,1,-1,-1,-1},{-1,-1,-1,-1,-1,-1}};
__device__ const int c_ntri[16]   = {0,1,1,2,1,2,2,1,1,2,2,1,2,1,1,0};
__device__ const int c_ncross[16] = {0,3,3,4,3,4,4,3,3,4,4,3,4,3,3,0};
__device__ const int c_edges[12] = {0,1,0,2,0,3,1,2,1,3,2,3};

// psum packing: m1 <<44 | m2 <<24 | ncross
#define PK(m1,m2,nc) (((u64)(m1) << 44) | ((u64)(m2) << 24) | (u64)(nc))
// ebin packing: a <<40 | b <<22 | seq; key36 = p>>22; group = key36>>SUBSH

// ---------------- generic exclusive scan (templated, 3 kernels) ----------------
#define SCAN_B 256
#define SCAN_I 8
#define SCAN_TILE (SCAN_B*SCAN_I)

template<typename T>
__global__ void k_scan_partial(const T* __restrict__ in, T* __restrict__ partials, int n){
  __shared__ T sm[SCAN_B];
  int b = blockIdx.x;
  long long base = (long long)b*SCAN_TILE;
  T sum = 0;
  for (int i = threadIdx.x; i < SCAN_TILE; i += SCAN_B){
    long long idx = base + i;
    if (idx < n) sum += in[idx];
  }
  sm[threadIdx.x] = sum; __syncthreads();
  for (int s = SCAN_B/2; s > 0; s >>= 1){
    if ((int)threadIdx.x < s) sm[threadIdx.x] += sm[threadIdx.x + s];
    __syncthreads();
  }
  if (threadIdx.x == 0) partials[b] = sm[0];
}

template<typename T>
__global__ void k_scan_blocksums(T* __restrict__ partials, int nb, T* __restrict__ total_out){
  __shared__ T sm[SCAN_B];
  T carry = 0;
  for (int base = 0; base < nb; base += SCAN_B){
    int i = base + (int)threadIdx.x;
    T v = (i < nb) ? partials[i] : (T)0;
    sm[threadIdx.x] = v; __syncthreads();
    for (int off = 1; off < SCAN_B; off <<= 1){
      T t = ((int)threadIdx.x >= off) ? sm[threadIdx.x - off] : (T)0;
      __syncthreads();
      sm[threadIdx.x] += t;
      __syncthreads();
    }
    if (i < nb) partials[i] = carry + sm[threadIdx.x] - v;  // exclusive
    T tilesum = sm[SCAN_B-1];
    __syncthreads();
    carry += tilesum;
  }
  if (threadIdx.x == 0 && total_out) *total_out = carry;
}

template<typename T>
__global__ void k_scan_apply(const T* __restrict__ in, T* __restrict__ out,
                             const T* __restrict__ partials, int n){
  __shared__ T sm[SCAN_B];
  int b = blockIdx.x;
  long long base = (long long)b*SCAN_TILE + (long long)threadIdx.x*SCAN_I;
  T v[SCAN_I]; T s = 0;
  #pragma unroll
  for (int k = 0; k < SCAN_I; k++){ long long idx = base + k; v[k] = (idx < n) ? in[idx] : (T)0; s += v[k]; }
  sm[threadIdx.x] = s; __syncthreads();
  for (int off = 1; off < SCAN_B; off <<= 1){
    T t = ((int)threadIdx.x >= off) ? sm[threadIdx.x - off] : (T)0;
    __syncthreads();
    sm[threadIdx.x] += t;
    __syncthreads();
  }
  T excl = sm[threadIdx.x] - s + partials[b];
  #pragma unroll
  for (int k = 0; k < SCAN_I; k++){ long long idx = base + k; if (idx < n) out[idx] = excl; excl += v[k]; }
}

template<typename T>
static void run_scan(const T* in, T* out, int n, T* partials, hipStream_t s){
  int nb = (n + SCAN_TILE - 1) / SCAN_TILE;
  k_scan_partial<T><<<nb, SCAN_B, 0, s>>>(in, partials, n);
  k_scan_blocksums<T><<<1, SCAN_B, 0, s>>>(partials, nb, out + n);  // total -> out[n]
  k_scan_apply<T><<<nb, SCAN_B, 0, s>>>(in, out, partials, n);
}

// ---------------- pipeline kernels ----------------

// fused: per-tet occupancy pattern + (m1,m2,ncross) pack + coarse-bin histogram
__global__ void k_classify_hist(const int* __restrict__ tet, const float* __restrict__ sdf,
                                int* __restrict__ tetinfo, u64* __restrict__ pk,
                                int* __restrict__ blockHist){
  __shared__ int h[NBIN];
  int blk = blockIdx.x;
  for (int j = threadIdx.x; j < NBIN; j += 256) h[j] = 0;
  __syncthreads();
  int t0 = blk*TILE_T;
  for (int k = 0; k < TILE_T/256; k++){
    int t = t0 + k*256 + threadIdx.x;
    if (t < kNT){
      int4 v4 = ((const int4*)tet)[t];
      int pat = ((sdf[v4.x] > 0.0f) ? 1 : 0) | ((sdf[v4.y] > 0.0f) ? 2 : 0)
              | ((sdf[v4.z] > 0.0f) ? 4 : 0) | ((sdf[v4.w] > 0.0f) ? 8 : 0);
      tetinfo[t] = pat;
      int nt_ = c_ntri[pat];
      pk[t] = PK(nt_ == 1, nt_ == 2, c_ncross[pat]);
      if (pat != 0 && pat != 15){
        int vv[4] = {v4.x, v4.y, v4.z, v4.w};
        #pragma unroll
        for (int e = 0; e < 6; e++){
          int i0 = c_edges[2*e], i1 = c_edges[2*e+1];
          if (((pat >> i0) & 1) != ((pat >> i1) & 1)){
            int a = vv[i0], b = vv[i1]; if (a > b){ int tm = a; a = b; b = tm; }
            atomicAdd(&h[a >> 8], 1);
          }
        }
      }
    }
  }
  __syncthreads();
  for (int j = threadIdx.x; j < NBIN; j += 256) blockHist[j*NH + blk] = h[j];  // bin-major
}

// scatter instances to bin-grouped buffer via LDS cursors (payload = seq)
__global__ void k_scatter(const int* __restrict__ tet, const int* __restrict__ tetinfo,
                          const u64* __restrict__ psum, const int* __restrict__ bhScan,
                          u64* __restrict__ ebin){
  __shared__ int c[NBIN];
  int blk = blockIdx.x;
  for (int j = threadIdx.x; j < NBIN; j += 256) c[j] = bhScan[j*NH + blk];
  __syncthreads();
  int t0 = blk*TILE_T;
  for (int k = 0; k < TILE_T/256; k++){
    int t = t0 + k*256 + threadIdx.x;
    if (t < kNT){
      int pat = tetinfo[t];
      if (pat != 0 && pat != 15){
        int4 v4 = ((const int4*)tet)[t];
        int vv[4] = {v4.x, v4.y, v4.z, v4.w};
        int seq = (int)(psum[t] & 0xFFFFFF);
        #pragma unroll
        for (int e = 0; e < 6; e++){
          int i0 = c_edges[2*e], i1 = c_edges[2*e+1];
          if (((pat >> i0) & 1) != ((pat >> i1) & 1)){
            int a = vv[i0], b = vv[i1]; if (a > b){ int tm = a; a = b; b = tm; }
            int pos = atomicAdd(&c[a >> 8], 1);
            ebin[pos] = ((u64)(unsigned)a << 40) | ((u64)(unsigned)b << 22) | (unsigned)seq;
            seq++;
          }
        }
      }
    }
  }
}

// per coarse bin: regroup by fine key (a&255)<<3 | b>>15.
// efin ends up globally sorted by (a, b>>15) -> groups are tiny (k ~ 1.5).
__global__ void k_fine(const int* __restrict__ bhScan, const u64* __restrict__ ebin,
                       u64* __restrict__ efin){
  __shared__ int h[FINEB];
  __shared__ int ss[256];
  int bin = blockIdx.x;
  int binStart = bhScan[bin*NH];
  int binEnd   = bhScan[(bin+1)*NH];     // scan stores total at [n] for the last bin
  int a0 = bin << 8;
  for (int j = threadIdx.x; j < FINEB; j += 256) h[j] = 0;
  __syncthreads();
  for (int i = binStart + threadIdx.x; i < binEnd; i += 256){
    u64 p = ebin[i];
    int a = (int)(p >> 40);
    int bh = (int)((p >> 22) & 0x3FFFF) >> SUBSH;
    atomicAdd(&h[((a - a0) << 3) | bh], 1);
  }
  __syncthreads();
  int tid = threadIdx.x;
  int base8 = tid*8;
  int loc[8]; int s = 0;
  #pragma unroll
  for (int q = 0; q < 8; q++){ loc[q] = h[base8+q]; s += loc[q]; }
  ss[tid] = s; __syncthreads();
  for (int off = 1; off < 256; off <<= 1){
    int v = (tid >= off) ? ss[tid - off] : 0;
    __syncthreads();
    ss[tid] += v;
    __syncthreads();
  }
  int excl = ss[tid] - s;
  #pragma unroll
  for (int q = 0; q < 8; q++){ h[base8+q] = excl; excl += loc[q]; }
  __syncthreads();
  for (int i = binStart + tid; i < binEnd; i += 256){
    u64 p = ebin[i];
    int a = (int)(p >> 40);
    int bh = (int)((p >> 22) & 0x3FFFF) >> SUBSH;
    int pos = binStart + atomicAdd(&h[((a - a0) << 3) | bh], 1);
    efin[pos] = p;
  }
}

// per-block count of first-occurrence items (no CAP-sized intermediates)
__global__ void k_fcount(const u64* __restrict__ efin, const int* __restrict__ totp,
                         int* __restrict__ blockAgg){
  __shared__ u64 ld[FW];
  __shared__ unsigned char fl[FW];
  __shared__ int wsum[4];
  int total = *totp;
  int tid = threadIdx.x;
  long long base = (long long)blockIdx.x * FB;
  if (base >= total){ if (tid == 0) blockAgg[blockIdx.x] = 0; return; }
  for (int x = tid; x < FW; x += FB){
    long long g = base - FH + x;
    ld[x] = (g >= 0 && g < total) ? (efin[g] >> 22) : ~0ULL;
  }
  __syncthreads();
  for (int x = tid; x < FW; x += FB){
    u64 key = ld[x]; u64 grp = key >> SUBSH;
    unsigned char f = 1;
    for (int y = x-1; y >= 0; y--){
      u64 ky = ld[y];
      if ((ky >> SUBSH) != grp) break;
      if (ky == key){ f = 0; break; }
    }
    fl[x] = f;
  }
  __syncthreads();
  long long gi = base + tid;
  int flag = 0;
  if (gi < total){
    int x = FH + tid;
    u64 key = ld[x]; u64 grp = key >> SUBSH;
    int sx = x; while (sx > 0 && (ld[sx-1] >> SUBSH) == grp) sx--;
    if (sx > 0) flag = fl[x];
    else {
      long long s = gi; while (s > 0 && ((efin[s-1] >> 22) >> SUBSH) == grp) s--;
      flag = 1;
      for (long long j = s; j < gi; j++) if ((efin[j] >> 22) == key){ flag = 0; break; }
    }
  }
  unsigned long long bal = __ballot(flag);
  if ((tid & 63) == 0) wsum[tid >> 6] = __popcll(bal);
  __syncthreads();
  if (tid == 0) blockAgg[blockIdx.x] = wsum[0] + wsum[1] + wsum[2] + wsum[3];
}

// fused flags+rank+emit: r = blockPrefix + window-prefix + rank; verts + rankBySeq scatter
__global__ void k_emit2(const u64* __restrict__ efin, const int* __restrict__ totp,
                        const int* __restrict__ blockPrefix,
                        const float* __restrict__ pos, const float* __restrict__ sdf,
                        float* __restrict__ out, int* __restrict__ rankBySeq){
  __shared__ u64 ld[FW];
  __shared__ unsigned char fl[FW];
  __shared__ int fp[FW];      // exclusive prefix of fl over window
  __shared__ int ps[FW/2];    // 160 pair sums
  int total = *totp;
  int tid = threadIdx.x;
  long long base = (long long)blockIdx.x * FB;
  if (base >= total) return;
  for (int x = tid; x < FW; x += FB){
    long long g = base - FH + x;
    ld[x] = (g >= 0 && g < total) ? (efin[g] >> 22) : ~0ULL;
  }
  __syncthreads();
  for (int x = tid; x < FW; x += FB){
    u64 key = ld[x]; u64 grp = key >> SUBSH;
    unsigned char f = 1;
    for (int y = x-1; y >= 0; y--){
      u64 ky = ld[y];
      if ((ky >> SUBSH) != grp) break;
      if (ky == key){ f = 0; break; }
    }
    fl[x] = f;
  }
  __syncthreads();
  // exclusive prefix fp[] of fl[] (pair-sum Hillis-Steele over 160)
  if (tid < FW/2) ps[tid] = (int)fl[2*tid] + (int)fl[2*tid+1];
  __syncthreads();
  for (int off = 1; off < FW/2; off <<= 1){
    int v = (tid >= off && tid < FW/2) ? ps[tid-off] : 0;
    __syncthreads();
    if (tid < FW/2) ps[tid] += v;
    __syncthreads();
  }
  if (tid < FW/2){
    int a0 = fl[2*tid], a1 = fl[2*tid+1];
    int excl = ps[tid] - a0 - a1;
    fp[2*tid] = excl; fp[2*tid+1] = excl + a0;
  }
  __syncthreads();
  long long gi = base + tid;
  if (gi >= total) return;
  int blkPref = blockPrefix[blockIdx.x];
  // if a single group spans [window-left .. base], fp counts in [FH,*) are unreliable
  bool spanL = (base > 0) && ((ld[0] >> SUBSH) == (ld[FH] >> SUBSH));
  int x = FH + tid;
  u64 key = ld[x]; u64 grp = key >> SUBSH;
  int sx = x; while (sx > 0 && (ld[sx-1] >> SUBSH) == grp) sx--;
  int ex = x+1; while (ex < FW && (ld[ex] >> SUBSH) == grp) ex++;
  int r, first;
  if (sx > 0 && ex < FW && !spanL){
    first = fl[x];
    int rk = 0;
    for (int y = sx; y < ex; y++) if (fl[y] && ld[y] < key) rk++;
    r = blkPref + (fp[sx] - fp[FH]) + rk;
  } else {
    // fully general slow path (rare: group crosses window edge)
    long long s = gi; while (s > 0 && ((efin[s-1] >> 22) >> SUBSH) == grp) s--;
    long long e = gi + 1; while (e < total && ((efin[e] >> 22) >> SUBSH) == grp) e++;
    first = 1;
    for (long long j = s; j < gi; j++) if ((efin[j] >> 22) == key){ first = 0; break; }
    int rk = 0;
    for (long long j = s; j < e; j++){
      u64 kj = efin[j] >> 22;
      if (kj < key){
        bool fj = true;
        for (long long l = s; l < j; l++) if ((efin[l] >> 22) == kj){ fj = false; break; }
        if (fj) rk++;
      }
    }
    // #firsts in [0, s) = blockPrefix[s/FB] + #firsts in [block base of s, s)
    long long sb = (s / FB) * FB;
    int cnt = blockPrefix[(int)(s / FB)];
    for (long long j = sb; j < s; j++){
      u64 kj = efin[j] >> 22; u64 gj = kj >> SUBSH;
      long long gs = j; while (gs > 0 && ((efin[gs-1] >> 22) >> SUBSH) == gj) gs--;
      bool fj = true;
      for (long long l = gs; l < j; l++) if ((efin[l] >> 22) == kj){ fj = false; break; }
      if (fj) cnt++;
    }
    r = cnt + rk;
  }
  u64 p = efin[gi];
  rankBySeq[(int)(p & 0x3FFFFF)] = r;
  if (first){
    int a = (int)(p >> 40);
    int b = (int)((p >> 22) & 0x3FFFF);
    float sa = sdf[a], sb2 = sdf[b];
    float denom = sa - sb2;              // s = [sa,-sb]; never 0 for a crossing edge
    float w0 = (-sb2) / denom, w1 = sa / denom;
    out[3LL*r + 0] = pos[3*a+0]*w0 + pos[3*b+0]*w1;
    out[3LL*r + 1] = pos[3*a+1]*w0 + pos[3*b+1]*w1;
    out[3LL*r + 2] = pos[3*a+2]*w0 + pos[3*b+2]*w1;
  }
}

// faces + uv_idx: er[j] = rankBySeq[seq + j] — fully sequential reads
__global__ void k_faces(const int* __restrict__ tetinfo, const u64* __restrict__ psum,
                        const int* __restrict__ Nep, const int* __restrict__ rankBySeq,
                        float* __restrict__ out){
  int t = blockIdx.x*256 + threadIdx.x; if (t >= kNT) return;
  int pat = tetinfo[t];
  int nt_ = c_ntri[pat];
  if (nt_ == 0) return;
  u64 tot = psum[kNT];
  int Nm1 = (int)(tot >> 44), Nm2 = (int)((tot >> 24) & 0xFFFFF);
  int Ne = *Nep;
  long long faces_off = 3LL*Ne;
  long long uvidx_off = faces_off + 3LL*((long long)Nm1 + 2LL*Nm2) + UVS_FLOATS;
  u64 ps = psum[t];
  int m1v = (int)(ps >> 44), m2v = (int)((ps >> 24) & 0xFFFFF);
  int seq = (int)(ps & 0xFFFFFF);
  int er[6];
  int j = 0;
  #pragma unroll
  for (int e = 0; e < 6; e++){
    int i0 = c_edges[2*e], i1 = c_edges[2*e+1];
    if (((pat >> i0) & 1) != ((pat >> i1) & 1)){
      er[e] = rankBySeq[seq + j];
      j++;
    } else er[e] = -1;
  }
  for (int k = 0; k < nt_; k++){
    long long row = (nt_ == 1) ? (long long)m1v : ((long long)Nm1 + 2LL*m2v + k);
    #pragma unroll
    for (int c = 0; c < 3; c++){
      int slot = c_tri[pat][3*k + c];
      out[faces_off + 3*row + c] = (float)er[slot];
    }
    out[uvidx_off + 3*row + 0] = (float)(4*t);
    out[uvidx_off + 3*row + 1] = (float)(4*t + k + 1);
    out[uvidx_off + 3*row + 2] = (float)(4*t + k + 2);
  }
}

__global__ void k_uvs(const u64* __restrict__ psum, const int* __restrict__ Nep,
                      float* __restrict__ out){
  long long r = (long long)blockIdx.x*256 + threadIdx.x;
  if (r >= UVS_ROWS) return;
  u64 tot = psum[kNT];
  int Nm1 = (int)(tot >> 44), Nm2 = (int)((tot >> 24) & 0xFFFFF);
  int Ne = *Nep;
  long long off = 3LL*Ne + 3LL*((long long)Nm1 + 2LL*Nm2);
  int cell = (int)(r >> 2), k = (int)(r & 3);
  int iy = cell / kNUV, ix = cell - iy*kNUV;
  const float delta = (1.0f - 1.0f/895.0f) / 894.0f;   // linspace(0, 1-1/N, N) step, f32
  const float pad = 0.9f / 895.0f;
  float x = (float)ix * delta, y = (float)iy * delta;
  float u = x + ((k == 1 || k == 2) ? pad : 0.0f);
  float v = y + ((k >= 2) ? pad : 0.0f);
  out[off + 2*r]     = u;
  out[off + 2*r + 1] = v;
}

// ---------------- host ----------------
static inline int divup(int a, int b){ return (a + b - 1) / b; }

extern "C" void kernel_launch(void* const* d_in, const int* in_sizes, int n_in,
                              void* d_out, int out_size, void* d_ws, size_t ws_size,
                              hipStream_t stream){
  const float* pos = (const float*)d_in[0];
  const float* sdf = (const float*)d_in[1];
  const int*   tet = (const int*)d_in[2];
  float* out = (float*)d_out;

  char* ws = (char*)d_ws;
  size_t off = 0;
  auto alloc = [&](size_t bytes) -> char* {
    char* p = ws + off; off += (bytes + 255) & ~(size_t)255; return p;
  };
  int* tetinfo     = (int*)alloc((size_t)kNT*4);
  u64* pk          = (u64*)alloc((size_t)kNT*8);
  u64* psum        = (u64*)alloc((size_t)(kNT+1)*8);
  int* blockHist   = (int*)alloc((size_t)NBIN*NH*4);
  int* bhScan      = (int*)alloc((size_t)(NBIN*NH+1)*4);
  u64* ebin        = (u64*)alloc((size_t)CAP*8);
  u64* efin        = (u64*)alloc((size_t)CAP*8);
  int* rankBySeq   = (int*)alloc((size_t)CAP*4);
  int* blockAgg    = (int*)alloc((size_t)(NFB+1)*4);
  u64* part64      = (u64*)alloc(4096*8);
  int* partI       = (int*)alloc(4096*4);
  if (off > ws_size){
    fprintf(stderr, "[dmtet] workspace too small: need %zu have %zu\n", off, ws_size);
    return;
  }

  k_classify_hist<<<NH, 256, 0, stream>>>(tet, sdf, tetinfo, pk, blockHist);
  run_scan<u64>(pk, psum, kNT, part64, stream);
  run_scan<int>(blockHist, bhScan, NBIN*NH, partI, stream);
  k_scatter<<<NH, 256, 0, stream>>>(tet, tetinfo, psum, bhScan, ebin);
  k_fine<<<NBIN, 256, 0, stream>>>(bhScan, ebin, efin);
  k_fcount<<<NFB, FB, 0, stream>>>(efin, bhScan + NBIN*NH, blockAgg);
  k_scan_blocksums<int><<<1, SCAN_B, 0, stream>>>(blockAgg, NFB, blockAgg + NFB);
  k_emit2<<<NFB, FB, 0, stream>>>(efin, bhScan + NBIN*NH, blockAgg, pos, sdf, out, rankBySeq);
  k_faces<<<divup(kNT,256), 256, 0, stream>>>(tetinfo, psum, blockAgg + NFB, rankBySeq, out);
  k_uvs<<<divup((int)UVS_ROWS,256), 256, 0, stream>>>(psum, blockAgg + NFB, out);
}

// Round 10
// 234.963 us; speedup vs baseline: 1.3746x; 1.0909x over previous
//
#include <hip/hip_runtime.h>
#include <cstdio>
#include <cstdint>

typedef unsigned long long u64;

// ---------------- problem constants ----------------
static const int kNV = 200000;
static const int kNT = 800000;
static const int kNUV = 895;                       // ceil(sqrt((2*NT+1)//2))
#define UVS_ROWS   3204100LL                       // kNUV*kNUV*4
#define UVS_FLOATS 6408200LL                       // UVS_ROWS*2
#define CAP 3300000                                // max crossing-edge instances (<= 4*NT = 3.2M)

// counting-sort geometry
#define NH 392                                     // classify/hist/scatter blocks
#define TILE_T 2048                                // tets per block (NH*TILE_T >= kNT)
#define BINW 256                                   // a-values per coarse bin
#define NBIN 782                                   // ceil(200000/256)
#define SUBSH 15                                   // group key = (a, b>>SUBSH)
#define FINEB 2048                                 // BINW * (1<<(18-SUBSH)) fine cursors

// flags window geometry
#define FB 256
#define FH 32
#define FW (FB + 2*FH)   // 320

__device__ const int c_tri[16][6] = {
    {-1,-1,-1,-1,-1,-1},{1,0,2,-1,-1,-1},{4,0,3,-1,-1,-1},{1,4,2,1,3,4},
    {3,1,5,-1,-1,-1},{2,3,0,2,5,3},{1,4,0,1,5,4},{4,2,5,-1,-1,-1},
    {4,5,2,-1,-1,-1},{4,1,0,4,5,1},{3,2,0,3,5,2},{1,3,5,-1,-1,-1},
    {4,1,2,4,3,1},{3,0,4,-1,-1,-1},{2,0,1,-1,-1,-1},{-1,-1,-1,-1,-1,-1}};
__device__ const int c_ntri[16]   = {0,1,1,2,1,2,2,1,1,2,2,1,2,1,1,0};
__device__ const int c_ncross[16] = {0,3,3,4,3,4,4,3,3,4,4,3,4,3,3,0};
__device__ const int c_edges[12] = {0,1,0,2,0,3,1,2,1,3,2,3};

// psum packing: m1 <<44 | m2 <<24 | ncross
#define PK(m1,m2,nc) (((u64)(m1) << 44) | ((u64)(m2) << 24) | (u64)(nc))
// ebin packing: a <<40 | b <<22 | seq; key36 = p>>22; group = key36>>SUBSH

// ---------------- generic exclusive scan (templated, 3 kernels) ----------------
#define SCAN_B 256
#define SCAN_I 8
#define SCAN_TILE (SCAN_B*SCAN_I)

template<typename T>
__global__ void k_scan_partial(const T* __restrict__ in, T* __restrict__ partials, int n){
  __shared__ T sm[SCAN_B];
  int b = blockIdx.x;
  long long base = (long long)b*SCAN_TILE;
  T sum = 0;
  for (int i = threadIdx.x; i < SCAN_TILE; i += SCAN_B){
    long long idx = base + i;
    if (idx < n) sum += in[idx];
  }
  sm[threadIdx.x] = sum; __syncthreads();
  for (int s = SCAN_B/2; s > 0; s >>= 1){
    if ((int)threadIdx.x < s) sm[threadIdx.x] += sm[threadIdx.x + s];
    __syncthreads();
  }
  if (threadIdx.x == 0) partials[b] = sm[0];
}

template<typename T>
__global__ void k_scan_blocksums(T* __restrict__ partials, int nb, T* __restrict__ total_out){
  __shared__ T sm[SCAN_B];
  T carry = 0;
  for (int base = 0; base < nb; base += SCAN_B){
    int i = base + (int)threadIdx.x;
    T v = (i < nb) ? partials[i] : (T)0;
    sm[threadIdx.x] = v; __syncthreads();
    for (int off = 1; off < SCAN_B; off <<= 1){
      T t = ((int)threadIdx.x >= off) ? sm[threadIdx.x - off] : (T)0;
      __syncthreads();
      sm[threadIdx.x] += t;
      __syncthreads();
    }
    if (i < nb) partials[i] = carry + sm[threadIdx.x] - v;  // exclusive
    T tilesum = sm[SCAN_B-1];
    __syncthreads();
    carry += tilesum;
  }
  if (threadIdx.x == 0 && total_out) *total_out = carry;
}

template<typename T>
__global__ void k_scan_apply(const T* __restrict__ in, T* __restrict__ out,
                             const T* __restrict__ partials, int n){
  __shared__ T sm[SCAN_B];
  int b = blockIdx.x;
  long long base = (long long)b*SCAN_TILE + (long long)threadIdx.x*SCAN_I;
  T v[SCAN_I]; T s = 0;
  #pragma unroll
  for (int k = 0; k < SCAN_I; k++){ long long idx = base + k; v[k] = (idx < n) ? in[idx] : (T)0; s += v[k]; }
  sm[threadIdx.x] = s; __syncthreads();
  for (int off = 1; off < 256; off <<= 1){
    T t = ((int)threadIdx.x >= off) ? sm[threadIdx.x - off] : (T)0;
    __syncthreads();
    sm[threadIdx.x] += t;
    __syncthreads();
  }
  T excl = sm[threadIdx.x] - s + partials[b];
  #pragma unroll
  for (int k = 0; k < SCAN_I; k++){ long long idx = base + k; if (idx < n) out[idx] = excl; excl += v[k]; }
}

template<typename T>
static void run_scan(const T* in, T* out, int n, T* partials, hipStream_t s){
  int nb = (n + SCAN_TILE - 1) / SCAN_TILE;
  k_scan_partial<T><<<nb, SCAN_B, 0, s>>>(in, partials, n);
  k_scan_blocksums<T><<<1, SCAN_B, 0, s>>>(partials, nb, out + n);  // total -> out[n]
  k_scan_apply<T><<<nb, SCAN_B, 0, s>>>(in, out, partials, n);
}

// ---------------- pipeline kernels ----------------

// fused: per-tet pattern + (m1,m2,ncross) pack + coarse-bin histogram + PK block-partials
__global__ void k_classify_hist(const int* __restrict__ tet, const float* __restrict__ sdf,
                                int* __restrict__ tetinfo, u64* __restrict__ pk,
                                int* __restrict__ blockHist, u64* __restrict__ pkPart){
  __shared__ int h[NBIN];
  __shared__ u64 red[256];
  int blk = blockIdx.x;
  for (int j = threadIdx.x; j < NBIN; j += 256) h[j] = 0;
  __syncthreads();
  int t0 = blk*TILE_T;
  u64 myPk = 0;
  for (int k = 0; k < TILE_T/256; k++){
    int t = t0 + k*256 + threadIdx.x;
    if (t < kNT){
      int4 v4 = ((const int4*)tet)[t];
      int pat = ((sdf[v4.x] > 0.0f) ? 1 : 0) | ((sdf[v4.y] > 0.0f) ? 2 : 0)
              | ((sdf[v4.z] > 0.0f) ? 4 : 0) | ((sdf[v4.w] > 0.0f) ? 8 : 0);
      tetinfo[t] = pat;
      int nt_ = c_ntri[pat];
      u64 pv = PK(nt_ == 1, nt_ == 2, c_ncross[pat]);
      pk[t] = pv;
      myPk += pv;                        // per-block fields: m1,m2<=2048<2^20, nc<=8192<2^24 ok
      if (pat != 0 && pat != 15){
        int vv[4] = {v4.x, v4.y, v4.z, v4.w};
        #pragma unroll
        for (int e = 0; e < 6; e++){
          int i0 = c_edges[2*e], i1 = c_edges[2*e+1];
          if (((pat >> i0) & 1) != ((pat >> i1) & 1)){
            int a = vv[i0], b = vv[i1]; if (a > b){ int tm = a; a = b; b = tm; }
            atomicAdd(&h[a >> 8], 1);
          }
        }
      }
    }
  }
  red[threadIdx.x] = myPk;
  __syncthreads();
  for (int s = 128; s > 0; s >>= 1){
    if ((int)threadIdx.x < s) red[threadIdx.x] += red[threadIdx.x + s];
    __syncthreads();
  }
  if (threadIdx.x == 0) pkPart[blk] = red[0];
  for (int j = threadIdx.x; j < NBIN; j += 256) blockHist[j*NH + blk] = h[j];  // bin-major
}

// scatter instances to bin-grouped buffer via LDS cursors (payload = seq)
__global__ void k_scatter(const int* __restrict__ tet, const int* __restrict__ tetinfo,
                          const u64* __restrict__ psum, const int* __restrict__ bhScan,
                          u64* __restrict__ ebin){
  __shared__ int c[NBIN];
  int blk = blockIdx.x;
  for (int j = threadIdx.x; j < NBIN; j += 256) c[j] = bhScan[j*NH + blk];
  __syncthreads();
  int t0 = blk*TILE_T;
  for (int k = 0; k < TILE_T/256; k++){
    int t = t0 + k*256 + threadIdx.x;
    if (t < kNT){
      int pat = tetinfo[t];
      if (pat != 0 && pat != 15){
        int4 v4 = ((const int4*)tet)[t];
        int vv[4] = {v4.x, v4.y, v4.z, v4.w};
        int seq = (int)(psum[t] & 0xFFFFFF);
        #pragma unroll
        for (int e = 0; e < 6; e++){
          int i0 = c_edges[2*e], i1 = c_edges[2*e+1];
          if (((pat >> i0) & 1) != ((pat >> i1) & 1)){
            int a = vv[i0], b = vv[i1]; if (a > b){ int tm = a; a = b; b = tm; }
            int pos = atomicAdd(&c[a >> 8], 1);
            ebin[pos] = ((u64)(unsigned)a << 40) | ((u64)(unsigned)b << 22) | (unsigned)seq;
            seq++;
          }
        }
      }
    }
  }
}

// per coarse bin: regroup by fine key (a&255)<<3 | b>>15.
// efin ends up globally sorted by (a, b>>15) -> groups for k_flags are tiny (k ~ 1.5).
__global__ void k_fine(const int* __restrict__ bhScan, const u64* __restrict__ ebin,
                       u64* __restrict__ efin){
  __shared__ int h[FINEB];
  __shared__ int ss[256];
  int bin = blockIdx.x;
  int binStart = bhScan[bin*NH];
  int binEnd   = bhScan[(bin+1)*NH];     // scan stores total at [n] for the last bin
  int a0 = bin << 8;
  for (int j = threadIdx.x; j < FINEB; j += 256) h[j] = 0;
  __syncthreads();
  for (int i = binStart + threadIdx.x; i < binEnd; i += 256){
    u64 p = ebin[i];
    int a = (int)(p >> 40);
    int bh = (int)((p >> 22) & 0x3FFFF) >> SUBSH;
    atomicAdd(&h[((a - a0) << 3) | bh], 1);
  }
  __syncthreads();
  int tid = threadIdx.x;
  int base8 = tid*8;
  int loc[8]; int s = 0;
  #pragma unroll
  for (int q = 0; q < 8; q++){ loc[q] = h[base8+q]; s += loc[q]; }
  ss[tid] = s; __syncthreads();
  for (int off = 1; off < 256; off <<= 1){
    int v = (tid >= off) ? ss[tid - off] : 0;
    __syncthreads();
    ss[tid] += v;
    __syncthreads();
  }
  int excl = ss[tid] - s;
  #pragma unroll
  for (int q = 0; q < 8; q++){ h[base8+q] = excl; excl += loc[q]; }
  __syncthreads();
  for (int i = binStart + tid; i < binEnd; i += 256){
    u64 p = ebin[i];
    int a = (int)(p >> 40);
    int bh = (int)((p >> 22) & 0x3FFFF) >> SUBSH;
    int pos = binStart + atomicAdd(&h[((a - a0) << 3) | bh], 1);
    efin[pos] = p;
  }
}

// item-parallel first/rank/off over (a,b>>15)-sorted efin, LDS window with halos.
__global__ void k_flags(const u64* __restrict__ efin, const int* __restrict__ totp,
                        int* __restrict__ firstI, unsigned* __restrict__ meta){
  __shared__ u64 ld[FW];
  __shared__ unsigned char fl[FW];
  int total = *totp;
  int tid = threadIdx.x;
  long long base = (long long)blockIdx.x * FB;
  long long gi = base + tid;
  if (base >= total){                       // pure tail block: zero-fill, no window
    if (gi < CAP){ firstI[gi] = 0; meta[gi] = 0; }
    return;
  }
  for (int x = tid; x < FW; x += FB){
    long long g = base - FH + x;
    ld[x] = (g >= 0 && g < total) ? (efin[g] >> 22) : ~0ULL;   // key36 = a<<18 | b
  }
  __syncthreads();
  for (int x = tid; x < FW; x += FB){
    u64 key = ld[x];
    u64 grp = key >> SUBSH;
    unsigned char f = 1;
    for (int y = x-1; y >= 0; y--){
      u64 ky = ld[y];
      if ((ky >> SUBSH) != grp) break;
      if (ky == key){ f = 0; break; }
    }
    fl[x] = f;
  }
  __syncthreads();
  if (gi < total){
    int x = FH + tid;
    u64 key = ld[x];
    u64 grp = key >> SUBSH;
    int sx = x; while (sx > 0 && (ld[sx-1] >> SUBSH) == grp) sx--;
    int ex = x+1; while (ex < FW && (ld[ex] >> SUBSH) == grp) ex++;
    int first, rank, off;
    if (sx > 0 && ex < FW){
      first = fl[x];
      int rk = 0;
      for (int y = sx; y < ex; y++) if (fl[y] && ld[y] < key) rk++;
      rank = rk; off = x - sx;
    } else {
      // slow path: group spans past the LDS window (statistically never)
      u64 keyg = efin[gi] >> 22;
      u64 grpg = keyg >> SUBSH;
      long long s = gi; while (s > 0 && ((efin[s-1] >> 22) >> SUBSH) == grpg) s--;
      long long e = gi + 1; while (e < total && ((efin[e] >> 22) >> SUBSH) == grpg) e++;
      int f = 1;
      for (long long j = s; j < gi; j++) if ((efin[j] >> 22) == keyg){ f = 0; break; }
      int rk = 0;
      for (long long j = s; j < e; j++){
        u64 kj = efin[j] >> 22;
        if (kj < keyg){
          bool fj = true;
          for (long long l = s; l < j; l++) if ((efin[l] >> 22) == kj){ fj = false; break; }
          if (fj) rk++;
        }
      }
      first = f; rank = rk; off = (int)(gi - s);
    }
    firstI[gi] = first;
    meta[gi] = (unsigned)rank | ((unsigned)off << 12) | ((unsigned)first << 24);
  } else if (gi < CAP){
    firstI[gi] = 0;      // straddling block's tail: zero-fill for exact CAP-length scan
    meta[gi] = 0;
  }
}

// item-parallel: r = fscan[group_start] + rank; verts (firsts) + rankBySeq scatter (NT store)
__global__ void k_emit(const u64* __restrict__ efin, const int* __restrict__ totp,
                       const int* __restrict__ fscan, const unsigned* __restrict__ meta,
                       const float* __restrict__ pos, const float* __restrict__ sdf,
                       float* __restrict__ out, int* __restrict__ rankBySeq){
  int total = *totp;
  int i = blockIdx.x*256 + threadIdx.x;
  if (i >= total) return;
  u64 p = efin[i];
  unsigned m = meta[i];
  int rank = m & 0xFFF, off = (m >> 12) & 0xFFF, first = (m >> 24) & 1;
  int r = fscan[i - off] + rank;
  __builtin_nontemporal_store(r, &rankBySeq[(int)(p & 0x3FFFFF)]);  // avoid 8x L2 dirtying
  if (first){
    int a = (int)(p >> 40);
    int b = (int)((p >> 22) & 0x3FFFF);
    float sa = sdf[a], sb = sdf[b];
    float denom = sa - sb;               // s = [sa,-sb]; never 0 for a crossing edge
    float w0 = (-sb) / denom;
    float w1 = sa / denom;
    out[3LL*r + 0] = pos[3*a+0]*w0 + pos[3*b+0]*w1;
    out[3LL*r + 1] = pos[3*a+1]*w0 + pos[3*b+1]*w1;
    out[3LL*r + 2] = pos[3*a+2]*w0 + pos[3*b+2]*w1;
  }
}

// faces + uv_idx: er[j] = rankBySeq[seq + j] — fully sequential reads
__global__ void k_faces(const int* __restrict__ tetinfo, const u64* __restrict__ psum,
                        const int* __restrict__ fscan, const int* __restrict__ rankBySeq,
                        float* __restrict__ out){
  int t = blockIdx.x*256 + threadIdx.x; if (t >= kNT) return;
  int pat = tetinfo[t];
  int nt_ = c_ntri[pat];
  if (nt_ == 0) return;
  u64 tot = psum[kNT];
  int Nm1 = (int)(tot >> 44), Nm2 = (int)((tot >> 24) & 0xFFFFF);
  int Ne = fscan[CAP];
  long long faces_off = 3LL*Ne;
  long long uvidx_off = faces_off + 3LL*((long long)Nm1 + 2LL*Nm2) + UVS_FLOATS;
  u64 ps = psum[t];
  int m1v = (int)(ps >> 44), m2v = (int)((ps >> 24) & 0xFFFFF);
  int seq = (int)(ps & 0xFFFFFF);
  int er[6];
  int j = 0;
  #pragma unroll
  for (int e = 0; e < 6; e++){
    int i0 = c_edges[2*e], i1 = c_edges[2*e+1];
    if (((pat >> i0) & 1) != ((pat >> i1) & 1)){
      er[e] = rankBySeq[seq + j];
      j++;
    } else er[e] = -1;
  }
  for (int k = 0; k < nt_; k++){
    long long row = (nt_ == 1) ? (long long)m1v : ((long long)Nm1 + 2LL*m2v + k);
    #pragma unroll
    for (int c = 0; c < 3; c++){
      int slot = c_tri[pat][3*k + c];
      out[faces_off + 3*row + c] = (float)er[slot];
    }
    out[uvidx_off + 3*row + 0] = (float)(4*t);
    out[uvidx_off + 3*row + 1] = (float)(4*t + k + 1);
    out[uvidx_off + 3*row + 2] = (float)(4*t + k + 2);
  }
}

__global__ void k_uvs(const u64* __restrict__ psum, const int* __restrict__ fscan,
                      float* __restrict__ out){
  long long r = (long long)blockIdx.x*256 + threadIdx.x;
  if (r >= UVS_ROWS) return;
  u64 tot = psum[kNT];
  int Nm1 = (int)(tot >> 44), Nm2 = (int)((tot >> 24) & 0xFFFFF);
  int Ne = fscan[CAP];
  long long off = 3LL*Ne + 3LL*((long long)Nm1 + 2LL*Nm2);
  int cell = (int)(r >> 2), k = (int)(r & 3);
  int iy = cell / kNUV, ix = cell - iy*kNUV;
  const float delta = (1.0f - 1.0f/895.0f) / 894.0f;   // linspace(0, 1-1/N, N) step, f32
  const float pad = 0.9f / 895.0f;
  float x = (float)ix * delta, y = (float)iy * delta;
  float u = x + ((k == 1 || k == 2) ? pad : 0.0f);
  float v = y + ((k >= 2) ? pad : 0.0f);
  if ((off & 1) == 0){                       // 8B-aligned fast path (uniform branch)
    float2 uv = make_float2(u, v);
    *reinterpret_cast<float2*>(&out[off + 2*r]) = uv;
  } else {
    out[off + 2*r]     = u;
    out[off + 2*r + 1] = v;
  }
}

// ---------------- host ----------------
static inline int divup(int a, int b){ return (a + b - 1) / b; }

extern "C" void kernel_launch(void* const* d_in, const int* in_sizes, int n_in,
                              void* d_out, int out_size, void* d_ws, size_t ws_size,
                              hipStream_t stream){
  const float* pos = (const float*)d_in[0];
  const float* sdf = (const float*)d_in[1];
  const int*   tet = (const int*)d_in[2];
  float* out = (float*)d_out;

  char* ws = (char*)d_ws;
  size_t off = 0;
  auto alloc = [&](size_t bytes) -> char* {
    char* p = ws + off; off += (bytes + 255) & ~(size_t)255; return p;
  };
  int* tetinfo     = (int*)alloc((size_t)kNT*4);
  u64* pk          = (u64*)alloc((size_t)kNT*8);
  u64* psum        = (u64*)alloc((size_t)(kNT+1)*8);
  int* blockHist   = (int*)alloc((size_t)NBIN*NH*4);
  int* bhScan      = (int*)alloc((size_t)(NBIN*NH+1)*4);
  u64* ebin        = (u64*)alloc((size_t)CAP*8);
  u64* efin        = (u64*)alloc((size_t)CAP*8);
  int* rankBySeq   = (int*)alloc((size_t)CAP*4);
  int* fscan       = (int*)alloc((size_t)(CAP+1)*4);
  u64* pkPart      = (u64*)alloc((size_t)NH*8);
  int* partI       = (int*)alloc(4096*4);
  // ebin is dead after k_fine: alias the flags outputs onto it
  int* firstI      = (int*)ebin;
  unsigned* meta   = (unsigned*)((char*)ebin + (size_t)CAP*4);
  if (off > ws_size){
    fprintf(stderr, "[dmtet] workspace too small: need %zu have %zu\n", off, ws_size);
    return;
  }

  k_classify_hist<<<NH, 256, 0, stream>>>(tet, sdf, tetinfo, pk, blockHist, pkPart);
  // psum scan: partials came from classify (TILE_T == SCAN_TILE == 2048)
  k_scan_blocksums<u64><<<1, SCAN_B, 0, stream>>>(pkPart, NH, psum + kNT);
  k_scan_apply<u64><<<divup(kNT,SCAN_TILE), SCAN_B, 0, stream>>>(pk, psum, pkPart, kNT);
  run_scan<int>(blockHist, bhScan, NBIN*NH, partI, stream);
  k_scatter<<<NH, 256, 0, stream>>>(tet, tetinfo, psum, bhScan, ebin);
  k_fine<<<NBIN, 256, 0, stream>>>(bhScan, ebin, efin);
  k_flags<<<divup(CAP,FB), FB, 0, stream>>>(efin, bhScan + NBIN*NH, firstI, meta);
  run_scan<int>(firstI, fscan, CAP, partI, stream);
  k_emit<<<divup(CAP,256), 256, 0, stream>>>(efin, bhScan + NBIN*NH, fscan, meta,
                                             pos, sdf, out, rankBySeq);
  k_faces<<<divup(kNT,256), 256, 0, stream>>>(tetinfo, psum, fscan, rankBySeq, out);
  k_uvs<<<divup((int)UVS_ROWS,256), 256, 0, stream>>>(psum, fscan, out);
}